// Round 1
// 3051.592 us; speedup vs baseline: 2.7128x; 2.7128x over previous
//
#include <hip/hip_runtime.h>
#include <hip/hip_bf16.h>

#define EDIM 1024
#define MDIM 4096
#define SEQ  2048
#define NB   4
#define ROWS 8192

typedef short bh8 __attribute__((ext_vector_type(8)));
typedef float f32x16 __attribute__((ext_vector_type(16)));

__device__ __forceinline__ float bf2f(unsigned short u) {
    return __uint_as_float(((unsigned int)u) << 16);
}
__device__ __forceinline__ unsigned short f2bf(float f) {
    unsigned int u = __float_as_uint(f);
    u += 0x7FFFu + ((u >> 16) & 1u);
    return (unsigned short)(u >> 16);
}
__device__ __forceinline__ void splitf(float v, unsigned short& h, unsigned short& l) {
    h = f2bf(v);
    l = f2bf(v - __uint_as_float(((unsigned int)h) << 16));
}
__device__ __forceinline__ void ld4f(const float* __restrict__ p, float* d) {
    const float4 v = *reinterpret_cast<const float4*>(p);
    d[0] = v.x; d[1] = v.y; d[2] = v.z; d[3] = v.w;
}
__device__ __forceinline__ void ld4h(const unsigned short* __restrict__ p, float* d) {
    const ushort4 v = *reinterpret_cast<const ushort4*>(p);
    d[0] = bf2f(v.x); d[1] = bf2f(v.y); d[2] = bf2f(v.z); d[3] = bf2f(v.w);
}

// dtype sniffer: flag=1 -> inputs are bf16, flag=0 -> f32
__global__ __launch_bounds__(64)
void sniff_k(const unsigned int* __restrict__ w, int* __restrict__ flag) {
    int ok = 0;
    const int base = threadIdx.x * 32;
#pragma unroll
    for (int i = 0; i < 32; ++i) {
        const unsigned int v = w[base + i];
        const unsigned int lo = v & 0xFFFFu, hi = v >> 16;
        const unsigned int el = (lo >> 7) & 0xFF, eh = (hi >> 7) & 0xFF;
        const bool okl = (lo == 0u) || (el >= 0x30u && el <= 0x7Eu);
        const bool okh = (hi == 0u) || (eh >= 0x30u && eh <= 0x7Eu);
        ok += (okl && okh) ? 1 : 0;
    }
#pragma unroll
    for (int off = 32; off > 0; off >>= 1) ok += __shfl_down(ok, off);
    if (threadIdx.x == 0) *flag = (ok > 1400) ? 1 : 0;
}

__global__ __launch_bounds__(256)
void gather_k(const int* __restrict__ x, const void* __restrict__ emb,
              float* __restrict__ h, const int* __restrict__ flagp) {
    const int bf = *flagp;
    const long long row = blockIdx.x;
    const int idx = x[row];
    const long long off = (long long)idx * EDIM + threadIdx.x * 4;
    float d[4];
    if (bf) ld4h((const unsigned short*)emb + off, d);
    else    ld4f((const float*)emb + off, d);
    *reinterpret_cast<float4*>(h + row * EDIM + threadIdx.x * 4)
        = make_float4(d[0], d[1], d[2], d[3]);
}

// Elementwise split: f32 [R,K] -> hi/lo bf16 [R,K] (no transpose).
__global__ __launch_bounds__(256)
void splitrows_k(const float* __restrict__ in, unsigned short* __restrict__ oh,
                 unsigned short* __restrict__ ol) {
    const long long i = ((long long)blockIdx.x * 256 + threadIdx.x) * 4;
    const float4 v = *reinterpret_cast<const float4*>(in + i);
    ushort4 h, l;
    splitf(v.x, h.x, l.x); splitf(v.y, h.y, l.y);
    splitf(v.z, h.z, l.z); splitf(v.w, h.w, l.w);
    *reinterpret_cast<ushort4*>(oh + i) = h;
    *reinterpret_cast<ushort4*>(ol + i) = l;
}

// Transpose + split: in [Kd, Nd] (f32, or bf16-if-flag when bF) -> hi/lo bf16 [Nd, Kd].
__global__ __launch_bounds__(256)
void splitT_k(const void* __restrict__ in, unsigned short* __restrict__ oh,
              unsigned short* __restrict__ ol, int Kd, int Nd,
              long long inOff, long long zIn, long long zOut,
              const int* __restrict__ flagp, int bF) {
    const int bf = bF ? *flagp : 0;
    const long long ib = inOff + (long long)blockIdx.z * zIn;
    const long long ob = (long long)blockIdx.z * zOut;
    const int k0 = blockIdx.y * 32, n0 = blockIdx.x * 32;
    __shared__ float t[32][33];
    const int c = threadIdx.x & 31, r0 = threadIdx.x >> 5;
#pragma unroll
    for (int i = 0; i < 4; ++i) {
        const int r = r0 + i * 8;
        const long long off = ib + (long long)(k0 + r) * Nd + n0 + c;
        t[r][c] = bf ? bf2f(((const unsigned short*)in)[off]) : ((const float*)in)[off];
    }
    __syncthreads();
#pragma unroll
    for (int i = 0; i < 4; ++i) {
        const int r = r0 + i * 8;
        const float v = t[c][r];
        unsigned short h, l;
        splitf(v, h, l);
        const long long oo = ob + (long long)(n0 + r) * Kd + k0 + c;
        oh[oo] = h; ol[oo] = l;
    }
}

// Split-bf16 MFMA GEMM: C[M,N] = op(A[M,K] @ B^T + bias), B given pre-split
// as hi/lo bf16 [N,K]. A is f32, split to hi/lo in-kernel (a*b ~= ah*bh +
// ah*bl + al*bh; lo*lo dropped, ~2^-18 relative).
// Tile: BM=256, BN=128, BK=64. 512 threads = 8 waves, 64x64 per wave,
// 2x2 fragments of v_mfma_f32_32x32x16_bf16.
template<bool BIAS, bool RELU, bool MASK>
__global__ __launch_bounds__(512, 2)
void mgemm_k(const float* __restrict__ A,
             const unsigned short* __restrict__ Bh,
             const unsigned short* __restrict__ Bl,
             const void* __restrict__ biasv, void* __restrict__ Cv,
             int M, int N, int K,
             long long sA, long long sB, long long sC,
             long long biasBase, float scale,
             const int* __restrict__ flagp, int bF, int cF) {
    const int flag = *flagp;
    const int bfB = bF ? flag : 0;
    const int bfC = cF ? flag : 0;

    A  += (long long)blockIdx.z * sA;
    Bh += (long long)blockIdx.z * sB;
    Bl += (long long)blockIdx.z * sB;
    const long long zC = (long long)blockIdx.z * sC;

    const int brow = blockIdx.y * 256;
    const int bcol = blockIdx.x * 128;

    const int tid  = threadIdx.x;
    const int lane = tid & 63;
    const int wave = tid >> 6;      // 0..7
    const int wr   = wave >> 1;     // 0..3  (M dir, 64 rows each)
    const int wc   = wave & 1;      // 0..1  (N dir, 64 cols each)
    const int l31  = lane & 31;
    const int lhi  = lane >> 5;

    // rows are 64 elems = 128 B = 8 x 16B blocks; block index XOR (row&7)
    // => conflict-free ds_read_b128 / staged writes.
    __shared__ __align__(16) unsigned short Ash[256 * 64];
    __shared__ __align__(16) unsigned short Asl[256 * 64];
    __shared__ __align__(16) unsigned short Bsh[128 * 64];
    __shared__ __align__(16) unsigned short Bsl[128 * 64];

    f32x16 acc[2][2];
#pragma unroll
    for (int a = 0; a < 2; ++a)
#pragma unroll
        for (int b = 0; b < 2; ++b)
#pragma unroll
            for (int e = 0; e < 16; ++e) acc[a][b][e] = 0.f;

    // A staging geometry: thread covers rows a_m0+32i, k elems a_kq..a_kq+3
    const int a_kq  = (tid & 15) * 4;
    const int a_m0  = tid >> 4;
    const int a_blk = (tid & 15) >> 1;
    const int a_off = (tid & 1) * 8;
    const float* Abase = A + (long long)(brow + a_m0) * K + a_kq;

    // B staging: thread covers row b_n, 16B blocks b_b0, b_b0+1
    const int b_n  = tid >> 2;
    const int b_b0 = (tid & 3) * 2;
    const long long boff = (long long)(bcol + b_n) * K + b_b0 * 8;
    const unsigned short* Bhb = Bh + boff;
    const unsigned short* Blb = Bl + boff;

    float4 areg[8];
    uint4  breg[4];

    auto gload = [&](int kk) {
#pragma unroll
        for (int i = 0; i < 8; ++i)
            areg[i] = *reinterpret_cast<const float4*>(Abase + (long long)32 * i * K + kk);
#pragma unroll
        for (int j = 0; j < 2; ++j) {
            breg[j]     = *reinterpret_cast<const uint4*>(Bhb + kk + j * 8);
            breg[2 + j] = *reinterpret_cast<const uint4*>(Blb + kk + j * 8);
        }
    };

    gload(0);

    for (int k0 = 0; k0 < K; k0 += 64) {
        __syncthreads();
        // stage A (split f32 -> hi/lo) into swizzled LDS
#pragma unroll
        for (int i = 0; i < 8; ++i) {
            const int m = a_m0 + 32 * i;
            const int byte = m * 128 + ((a_blk ^ (m & 7)) << 4) + a_off;
            unsigned short h0, h1, h2, h3, l0, l1, l2, l3;
            splitf(areg[i].x, h0, l0); splitf(areg[i].y, h1, l1);
            splitf(areg[i].z, h2, l2); splitf(areg[i].w, h3, l3);
            uint2 hp, lp;
            hp.x = (unsigned int)h0 | ((unsigned int)h1 << 16);
            hp.y = (unsigned int)h2 | ((unsigned int)h3 << 16);
            lp.x = (unsigned int)l0 | ((unsigned int)l1 << 16);
            lp.y = (unsigned int)l2 | ((unsigned int)l3 << 16);
            *reinterpret_cast<uint2*>(reinterpret_cast<char*>(Ash) + byte) = hp;
            *reinterpret_cast<uint2*>(reinterpret_cast<char*>(Asl) + byte) = lp;
        }
        // stage B (already split) into swizzled LDS
#pragma unroll
        for (int j = 0; j < 2; ++j) {
            const int blk  = b_b0 + j;
            const int byte = b_n * 128 + ((blk ^ (b_n & 7)) << 4);
            *reinterpret_cast<uint4*>(reinterpret_cast<char*>(Bsh) + byte) = breg[j];
            *reinterpret_cast<uint4*>(reinterpret_cast<char*>(Bsl) + byte) = breg[2 + j];
        }
        __syncthreads();
        if (k0 + 64 < K) gload(k0 + 64);   // prefetch next tile under compute

#pragma unroll
        for (int ks = 0; ks < 4; ++ks) {
            const int kb = ks * 2 + lhi;
            bh8 ah[2], al[2], bhf[2], blf[2];
#pragma unroll
            for (int mi = 0; mi < 2; ++mi) {
                const int r = wr * 64 + mi * 32 + l31;
                const int byte = r * 128 + ((kb ^ (r & 7)) << 4);
                ah[mi] = *reinterpret_cast<const bh8*>(reinterpret_cast<const char*>(Ash) + byte);
                al[mi] = *reinterpret_cast<const bh8*>(reinterpret_cast<const char*>(Asl) + byte);
            }
#pragma unroll
            for (int ni = 0; ni < 2; ++ni) {
                const int r = wc * 64 + ni * 32 + l31;
                const int byte = r * 128 + ((kb ^ (r & 7)) << 4);
                bhf[ni] = *reinterpret_cast<const bh8*>(reinterpret_cast<const char*>(Bsh) + byte);
                blf[ni] = *reinterpret_cast<const bh8*>(reinterpret_cast<const char*>(Bsl) + byte);
            }
#pragma unroll
            for (int mi = 0; mi < 2; ++mi)
#pragma unroll
                for (int ni = 0; ni < 2; ++ni) {
                    acc[mi][ni] = __builtin_amdgcn_mfma_f32_32x32x16_bf16(ah[mi], bhf[ni], acc[mi][ni], 0, 0, 0);
                    acc[mi][ni] = __builtin_amdgcn_mfma_f32_32x32x16_bf16(ah[mi], blf[ni], acc[mi][ni], 0, 0, 0);
                    acc[mi][ni] = __builtin_amdgcn_mfma_f32_32x32x16_bf16(al[mi], bhf[ni], acc[mi][ni], 0, 0, 0);
                }
        }
    }

    // epilogue: C/D layout (32x32): col = lane&31, row = (e&3)+8*(e>>2)+4*(lane>>5)
#pragma unroll
    for (int mi = 0; mi < 2; ++mi) {
        const int rbase = brow + wr * 64 + mi * 32 + 4 * lhi;
#pragma unroll
        for (int ni = 0; ni < 2; ++ni) {
            const int c = bcol + wc * 64 + ni * 32 + l31;
            float bv = 0.f;
            if (BIAS) {
                const long long bo = biasBase + c;
                bv = bfB ? bf2f(((const unsigned short*)biasv)[bo])
                         : ((const float*)biasv)[bo];
            }
#pragma unroll
            for (int e = 0; e < 16; ++e) {
                const int r = rbase + (e & 3) + 8 * (e >> 2);
                float v = acc[mi][ni][e];
                if (BIAS) v += bv;
                if (MASK) v = (c >= r) ? v * scale : -1e30f;
                if (RELU) v = fmaxf(v, 0.f);
                const long long off = zC + (long long)r * N + c;
                if (bfC) ((__hip_bfloat16*)Cv)[off] = __float2bfloat16(v);
                else     ((float*)Cv)[off] = v;
            }
        }
    }
}

__global__ __launch_bounds__(256)
void softmax_k(float* __restrict__ Sc) {
    float* row = Sc + (long long)blockIdx.y * SEQ * SEQ + (long long)blockIdx.x * SEQ;
    const int tid = threadIdx.x;

    float v[8];
    float m = -1e30f;
#pragma unroll
    for (int i = 0; i < 8; ++i) { v[i] = row[tid + i * 256]; m = fmaxf(m, v[i]); }
#pragma unroll
    for (int off = 32; off > 0; off >>= 1) m = fmaxf(m, __shfl_down(m, off));

    __shared__ float sm[4];
    __shared__ float ss[4];
    const int wid = tid >> 6, lane = tid & 63;
    if (lane == 0) sm[wid] = m;
    __syncthreads();
    const float mAll = fmaxf(fmaxf(sm[0], sm[1]), fmaxf(sm[2], sm[3]));

    float s = 0.f;
#pragma unroll
    for (int i = 0; i < 8; ++i) { v[i] = __expf(v[i] - mAll); s += v[i]; }
#pragma unroll
    for (int off = 32; off > 0; off >>= 1) s += __shfl_down(s, off);
    if (lane == 0) ss[wid] = s;
    __syncthreads();
    const float inv = 1.f / (ss[0] + ss[1] + ss[2] + ss[3]);
#pragma unroll
    for (int i = 0; i < 8; ++i) row[tid + i * 256] = v[i] * inv;
}

extern "C" void kernel_launch(void* const* d_in, const int* in_sizes, int n_in,
                              void* d_out, int out_size, void* d_ws, size_t ws_size,
                              hipStream_t stream) {
    const int*  x   = (const int*)d_in[0];
    const void* emb = d_in[1];
    const void* Wq  = d_in[2];
    const void* bq  = d_in[3];
    const void* Wk  = d_in[4];
    const void* bk  = d_in[5];
    const void* Wv  = d_in[6];
    const void* bv  = d_in[7];
    const void* W1  = d_in[8];
    const void* b1  = d_in[9];
    const void* W2  = d_in[10];
    const void* b2  = d_in[11];

    char* ws = (char*)d_ws;
    const long long SZ = 33554432LL;  // 8192*1024*4 bytes
    // Slot plan (total 7*SZ + 4 bytes, same footprint as previous version):
    //  0: h            / mid part     4-5: sc          / (4: pong, 5: Wslot)
    //  1: q            / mid part     6:   kxs         / att
    //  2: kx f32 -> vxs / mid part    7*SZ: flag
    //  3: vx f32       / mid part
    float* h    = (float*)(ws);
    float* q    = (float*)(ws + SZ);
    float* kx   = (float*)(ws + 2 * SZ);
    float* vx   = (float*)(ws + 3 * SZ);
    float* sc   = (float*)(ws + 4 * SZ);
    float* mid  = h;                       // [8192,4096] spans slots 0-3
    float* pong = sc;                      // slot 4 during MLP
    float* att  = (float*)(ws + 6 * SZ);
    unsigned short* wsl_h = (unsigned short*)(ws + 5 * SZ);   // weight slot (sc dead / not yet live)
    unsigned short* wsl_l = wsl_h + 4194304;                  // + 4096*1024 elems
    unsigned short* kxs_h = (unsigned short*)(ws + 6 * SZ);   // kx split (dead before att written)
    unsigned short* kxs_l = kxs_h + 8388608;                  // + 8192*1024 elems
    unsigned short* vxs_h = (unsigned short*)(ws + 2 * SZ);   // vx^T split (kx f32 dead)
    unsigned short* vxs_l = vxs_h + 8388608;
    int*   flag = (int*)(ws + 7 * SZ);

    const dim3 b256(256), b512(512);
    const long long SE = (long long)SEQ * EDIM;
    const long long SS = (long long)SEQ * SEQ;

    sniff_k<<<1, 64, 0, stream>>>((const unsigned int*)emb, flag);
    gather_k<<<ROWS, b256, 0, stream>>>(x, emb, h, flag);

    // QKV projections: W [E,E] -> split^T [N,K] into Wslot, then MFMA GEMM.
    splitT_k<<<dim3(EDIM / 32, EDIM / 32, 1), b256, 0, stream>>>(
        Wq, wsl_h, wsl_l, EDIM, EDIM, 0, 0, 0, flag, 1);
    mgemm_k<true, false, false><<<dim3(EDIM / 128, ROWS / 256, 1), b512, 0, stream>>>(
        h, wsl_h, wsl_l, bq, q, ROWS, EDIM, EDIM, 0, 0, 0, 0, 1.f, flag, 1, 0);
    splitT_k<<<dim3(EDIM / 32, EDIM / 32, 1), b256, 0, stream>>>(
        Wk, wsl_h, wsl_l, EDIM, EDIM, 0, 0, 0, flag, 1);
    mgemm_k<true, false, false><<<dim3(EDIM / 128, ROWS / 256, 1), b512, 0, stream>>>(
        h, wsl_h, wsl_l, bk, kx, ROWS, EDIM, EDIM, 0, 0, 0, 0, 1.f, flag, 1, 0);
    splitT_k<<<dim3(EDIM / 32, EDIM / 32, 1), b256, 0, stream>>>(
        Wv, wsl_h, wsl_l, EDIM, EDIM, 0, 0, 0, flag, 1);
    mgemm_k<true, false, false><<<dim3(EDIM / 128, ROWS / 256, 1), b512, 0, stream>>>(
        h, wsl_h, wsl_l, bv, vx, ROWS, EDIM, EDIM, 0, 0, 0, 0, 1.f, flag, 1, 0);

    // K: split rows (already [n,k] for the NT scores GEMM)
    splitrows_k<<<ROWS * EDIM / 1024, b256, 0, stream>>>(kx, kxs_h, kxs_l);
    // V: transpose+split per batch: [S,E] -> [E,S]
    splitT_k<<<dim3(EDIM / 32, SEQ / 32, NB), b256, 0, stream>>>(
        vx, vxs_h, vxs_l, SEQ, EDIM, 0, SE, SE, flag, 0);

    // scores = (q @ k^T) * scale, suffix mask
    mgemm_k<false, false, true><<<dim3(SEQ / 128, SEQ / 256, NB), b512, 0, stream>>>(
        q, kxs_h, kxs_l, nullptr, sc, SEQ, SEQ, EDIM, SE, SE, SS, 0, 0.03125f, flag, 0, 0);

    softmax_k<<<dim3(SEQ, NB), b256, 0, stream>>>(sc);

    // att = relu(w @ v)
    mgemm_k<false, true, false><<<dim3(EDIM / 128, SEQ / 256, NB), b512, 0, stream>>>(
        sc, vxs_h, vxs_l, nullptr, att, SEQ, EDIM, SEQ, SS, SE, SE, 0, 1.f, flag, 0, 0);

    // MLP: per layer convert W into Wslot, then GEMM.
    const float* cur = att;
    for (int i = 0; i < 4; ++i) {
        splitT_k<<<dim3(MDIM / 32, EDIM / 32, 1), b256, 0, stream>>>(
            W1, wsl_h, wsl_l, EDIM, MDIM, (long long)i * EDIM * MDIM, 0, 0, flag, 1);
        mgemm_k<true, true, false><<<dim3(MDIM / 128, ROWS / 256, 1), b512, 0, stream>>>(
            cur, wsl_h, wsl_l, b1, mid, ROWS, MDIM, EDIM, 0, 0, 0,
            (long long)i * MDIM, 1.f, flag, 1, 0);

        splitT_k<<<dim3(EDIM / 32, MDIM / 32, 1), b256, 0, stream>>>(
            W2, wsl_h, wsl_l, MDIM, EDIM, (long long)i * MDIM * EDIM, 0, 0, flag, 1);
        if (i < 3) {
            float* out = (cur == att) ? pong : att;
            mgemm_k<true, true, false><<<dim3(EDIM / 128, ROWS / 256, 1), b512, 0, stream>>>(
                mid, wsl_h, wsl_l, b2, out, ROWS, EDIM, MDIM, 0, 0, 0,
                (long long)i * EDIM, 1.f, flag, 1, 0);
            cur = out;
        } else {
            mgemm_k<true, true, false><<<dim3(EDIM / 128, ROWS / 256, 1), b512, 0, stream>>>(
                mid, wsl_h, wsl_l, b2, d_out, ROWS, EDIM, MDIM, 0, 0, 0,
                (long long)i * EDIM, 1.f, flag, 1, 1);
        }
    }
}

// Round 2
// 2485.805 us; speedup vs baseline: 3.3303x; 1.2276x over previous
//
#include <hip/hip_runtime.h>
#include <hip/hip_bf16.h>

#define EDIM 1024
#define MDIM 4096
#define SEQ  2048
#define NB   4
#define ROWS 8192

#define BM 128
#define BN 128
#define BK 32

typedef short bh8 __attribute__((ext_vector_type(8)));
typedef float f32x16 __attribute__((ext_vector_type(16)));

__device__ __forceinline__ float bf2f(unsigned short u) {
    return __uint_as_float(((unsigned int)u) << 16);
}
__device__ __forceinline__ unsigned short f2bf(float f) {
    unsigned int u = __float_as_uint(f);
    u += 0x7FFFu + ((u >> 16) & 1u);
    return (unsigned short)(u >> 16);
}
__device__ __forceinline__ void splitf(float v, unsigned short& h, unsigned short& l) {
    h = f2bf(v);
    l = f2bf(v - __uint_as_float(((unsigned int)h) << 16));
}
__device__ __forceinline__ void ld4f(const float* __restrict__ p, float* d) {
    const float4 v = *reinterpret_cast<const float4*>(p);
    d[0] = v.x; d[1] = v.y; d[2] = v.z; d[3] = v.w;
}
__device__ __forceinline__ void ld4h(const unsigned short* __restrict__ p, float* d) {
    const ushort4 v = *reinterpret_cast<const ushort4*>(p);
    d[0] = bf2f(v.x); d[1] = bf2f(v.y); d[2] = bf2f(v.z); d[3] = bf2f(v.w);
}

// fragment-tiled index: element (n,k) of a [N][K] B-matrix lives at
// (((n/32)*(K/16) + k/16)*2 + (k/8)%2)*32 + n%32)*8 + k%8
// so a wave's 64 lanes (lane = k8*32 + n31) read one contiguous 1KB chunk.
__device__ __forceinline__ long long tidx8(int n, int k, int KD16) {
    return ((((long long)(n >> 5) * KD16 + (k >> 4)) * 2 + ((k >> 3) & 1)) * 32 + (n & 31)) * 8;
}

// dtype sniffer: flag=1 -> inputs are bf16, flag=0 -> f32
__global__ __launch_bounds__(64)
void sniff_k(const unsigned int* __restrict__ w, int* __restrict__ flag) {
    int ok = 0;
    const int base = threadIdx.x * 32;
#pragma unroll
    for (int i = 0; i < 32; ++i) {
        const unsigned int v = w[base + i];
        const unsigned int lo = v & 0xFFFFu, hi = v >> 16;
        const unsigned int el = (lo >> 7) & 0xFF, eh = (hi >> 7) & 0xFF;
        const bool okl = (lo == 0u) || (el >= 0x30u && el <= 0x7Eu);
        const bool okh = (hi == 0u) || (eh >= 0x30u && eh <= 0x7Eu);
        ok += (okl && okh) ? 1 : 0;
    }
#pragma unroll
    for (int off = 32; off > 0; off >>= 1) ok += __shfl_down(ok, off);
    if (threadIdx.x == 0) *flag = (ok > 1400) ? 1 : 0;
}

__global__ __launch_bounds__(256)
void gather_k(const int* __restrict__ x, const void* __restrict__ emb,
              float* __restrict__ h, const int* __restrict__ flagp) {
    const int bf = *flagp;
    const long long row = blockIdx.x;
    const int idx = x[row];
    const long long off = (long long)idx * EDIM + threadIdx.x * 4;
    float d[4];
    if (bf) ld4h((const unsigned short*)emb + off, d);
    else    ld4f((const float*)emb + off, d);
    *reinterpret_cast<float4*>(h + row * EDIM + threadIdx.x * 4)
        = make_float4(d[0], d[1], d[2], d[3]);
}

// f32 [8192,1024] (4 batches of 2048 rows) -> split + fragment-tiled, per batch.
__global__ __launch_bounds__(256)
void splitrows_tiled_k(const float* __restrict__ in, unsigned short* __restrict__ oh,
                       unsigned short* __restrict__ ol) {
    const int rr = blockIdx.x * 2 + (threadIdx.x >> 7);
    const int chunk = threadIdx.x & 127;       // K/8 = 128
    const int k = chunk * 8;
    const float* p = in + (long long)rr * 1024 + k;
    float d[8];
    ld4f(p, d); ld4f(p + 4, d + 4);
    unsigned short h[8], l[8];
#pragma unroll
    for (int j = 0; j < 8; ++j) splitf(d[j], h[j], l[j]);
    const int z = rr >> 11, n = rr & 2047;
    const long long o = (long long)z * (2048LL * 1024) + tidx8(n, k, 64);
    uint4 hv, lv;
    hv.x = (unsigned)h[0] | ((unsigned)h[1] << 16);
    hv.y = (unsigned)h[2] | ((unsigned)h[3] << 16);
    hv.z = (unsigned)h[4] | ((unsigned)h[5] << 16);
    hv.w = (unsigned)h[6] | ((unsigned)h[7] << 16);
    lv.x = (unsigned)l[0] | ((unsigned)l[1] << 16);
    lv.y = (unsigned)l[2] | ((unsigned)l[3] << 16);
    lv.z = (unsigned)l[4] | ((unsigned)l[5] << 16);
    lv.w = (unsigned)l[6] | ((unsigned)l[7] << 16);
    *reinterpret_cast<uint4*>(oh + o) = hv;
    *reinterpret_cast<uint4*>(ol + o) = lv;
}

// Transpose + split + fragment-tile: in [Kd,Nd] (f32, or bf16 when bF&flag)
// -> hi/lo bf16 tiled [Nd,Kd].
__global__ __launch_bounds__(256)
void splitT_tiled_k(const void* __restrict__ in, unsigned short* __restrict__ oh,
                    unsigned short* __restrict__ ol, int Kd, int Nd,
                    long long inOff, long long zIn, long long zOut,
                    const int* __restrict__ flagp, int bF) {
    const int bf = bF ? *flagp : 0;
    const long long ib = inOff + (long long)blockIdx.z * zIn;
    const long long ob = (long long)blockIdx.z * zOut;
    const int k0 = blockIdx.y * 32, n0 = blockIdx.x * 32;
    const int KD16 = Kd >> 4;
    __shared__ float t[32][33];
    const int c = threadIdx.x & 31, r0 = threadIdx.x >> 5;
#pragma unroll
    for (int i = 0; i < 4; ++i) {
        const int r = r0 + i * 8;
        const long long off = ib + (long long)(k0 + r) * Nd + n0 + c;
        t[r][c] = bf ? bf2f(((const unsigned short*)in)[off]) : ((const float*)in)[off];
    }
    __syncthreads();
#pragma unroll
    for (int i = 0; i < 4; ++i) {
        const int r = r0 + i * 8;
        const float v = t[c][r];
        unsigned short hh, ll;
        splitf(v, hh, ll);
        const int n = n0 + r, k = k0 + c;
        const long long oo = ob + tidx8(n, k, KD16) + (k & 7);
        oh[oo] = hh; ol[oo] = ll;
    }
}

// Split-bf16 MFMA GEMM: C[M,N] = op(A[M,K] @ B^T + bias).
// A f32 (split in-kernel, staged to double-buffered LDS).
// B pre-split hi/lo bf16 in fragment-tiled layout, read direct from global.
// 128x128 tile, BK=32, 4 waves (64x64 each, 2x2 frags of 32x32x16), 3 blocks/CU.
template<bool BIAS, bool RELU, bool MASK>
__global__ __launch_bounds__(256, 3)
void mgemm_k(const float* __restrict__ A,
             const unsigned short* __restrict__ Bh,
             const unsigned short* __restrict__ Bl,
             const void* __restrict__ biasv, void* __restrict__ Cv,
             int M, int N, int K,
             long long sA, long long sB, long long sC,
             long long biasBase, float scale,
             const int* __restrict__ flagp, int bF, int cF) {
    const int flag = *flagp;
    const int bfBias = bF ? flag : 0;
    const int bfC = cF ? flag : 0;

    A  += (long long)blockIdx.z * sA;
    Bh += (long long)blockIdx.z * sB;
    Bl += (long long)blockIdx.z * sB;
    const long long zC = (long long)blockIdx.z * sC;

    // XCD remap: each XCD owns a contiguous bx-group; by-major inside
    // -> A panel reused back-to-back (L2), B panels L2-resident per XCD.
    const int GX = gridDim.x;
    const int f = blockIdx.y * GX + blockIdx.x;
    const int gxpc = GX >> 3;
    const int xcd = f & 7, p = f >> 3;
    const int bx = xcd * gxpc + (p % gxpc);
    const int by = p / gxpc;
    const int brow = by * BM, bcol = bx * BN;

    const int tid = threadIdx.x;
    const int lane = tid & 63, wave = tid >> 6;
    const int wr = wave >> 1, wc = wave & 1;
    const int l31 = lane & 31, lhi = lane >> 5;

    if (MASK && (bcol + BN - 1 < brow)) {
        // fully masked tile: write -1e30, skip all compute
#pragma unroll
        for (int mi = 0; mi < 2; ++mi) {
            const int rbase = brow + wr * 64 + mi * 32 + 4 * lhi;
#pragma unroll
            for (int ni = 0; ni < 2; ++ni) {
                const int c = bcol + wc * 64 + ni * 32 + l31;
#pragma unroll
                for (int e = 0; e < 16; ++e) {
                    const int r = rbase + (e & 3) + 8 * (e >> 2);
                    ((float*)Cv)[zC + (long long)r * N + c] = -1e30f;
                }
            }
        }
        return;
    }

    // double-buffered A LDS: rows of 32 bf16 = 64B = 4x16B blocks,
    // block-XOR swizzle by (row&3) -> uniform bank use on ds_read_b128.
    __shared__ __align__(16) unsigned short Ash[2][BM * BK];
    __shared__ __align__(16) unsigned short Asl[2][BM * BK];

    f32x16 acc[2][2];
#pragma unroll
    for (int a = 0; a < 2; ++a)
#pragma unroll
        for (int b = 0; b < 2; ++b)
#pragma unroll
            for (int e = 0; e < 16; ++e) acc[a][b][e] = 0.f;

    const int arow = tid >> 3;            // 0..31 (4 row-groups of 32)
    const int akq  = (tid & 7) * 4;       // k quad within BK
    const int ablk = (tid & 7) >> 1;
    const int asub = (tid & 1) * 8;
    const float* Ap = A + (long long)(brow + arow) * K + akq;

    const int KD16 = K >> 4;
    const long long bbase0 = ((long long)((bcol >> 5) + wc * 2 + 0) * KD16) * 512 + lane * 8;
    const long long bbase1 = ((long long)((bcol >> 5) + wc * 2 + 1) * KD16) * 512 + lane * 8;

    float4 areg[4];
    bh8 b0[4], b1[4];   // [h0,h1,l0,l1] for the two ks slots

    auto loadA = [&](int k0) {
#pragma unroll
        for (int i = 0; i < 4; ++i)
            areg[i] = *reinterpret_cast<const float4*>(Ap + (long long)32 * i * K + k0);
    };
    auto stageA = [&](int b) {
#pragma unroll
        for (int i = 0; i < 4; ++i) {
            const int m = arow + 32 * i;
            const int byt = m * 64 + ((ablk ^ (m & 3)) << 4) + asub;
            unsigned short h0, h1, h2, h3, l0, l1, l2, l3;
            splitf(areg[i].x, h0, l0); splitf(areg[i].y, h1, l1);
            splitf(areg[i].z, h2, l2); splitf(areg[i].w, h3, l3);
            uint2 hp, lp;
            hp.x = (unsigned)h0 | ((unsigned)h1 << 16);
            hp.y = (unsigned)h2 | ((unsigned)h3 << 16);
            lp.x = (unsigned)l0 | ((unsigned)l1 << 16);
            lp.y = (unsigned)l2 | ((unsigned)l3 << 16);
            *reinterpret_cast<uint2*>(reinterpret_cast<char*>(&Ash[b][0]) + byt) = hp;
            *reinterpret_cast<uint2*>(reinterpret_cast<char*>(&Asl[b][0]) + byt) = lp;
        }
    };

#define LOADB(dst, k4v) { \
    const long long kk_ = (long long)(k4v) * 512; \
    dst[0] = *reinterpret_cast<const bh8*>(Bh + bbase0 + kk_); \
    dst[1] = *reinterpret_cast<const bh8*>(Bh + bbase1 + kk_); \
    dst[2] = *reinterpret_cast<const bh8*>(Bl + bbase0 + kk_); \
    dst[3] = *reinterpret_cast<const bh8*>(Bl + bbase1 + kk_); }

#define AFRAG(dsth, dstl, MI) { \
    const int r_ = wr * 64 + (MI) * 32 + l31; \
    const int byt_ = r_ * 64 + ((kb ^ (r_ & 3)) << 4); \
    dsth = *reinterpret_cast<const bh8*>(reinterpret_cast<const char*>(&Ash[bufc][0]) + byt_); \
    dstl = *reinterpret_cast<const bh8*>(reinterpret_cast<const char*>(&Asl[bufc][0]) + byt_); }

#define COMPUTE_KS(KS, BS) { \
    const int kb = (KS) * 2 + lhi; \
    bh8 ah0, al0, ah1, al1; \
    AFRAG(ah0, al0, 0); AFRAG(ah1, al1, 1); \
    acc[0][0] = __builtin_amdgcn_mfma_f32_32x32x16_bf16(ah0, BS[0], acc[0][0], 0, 0, 0); \
    acc[0][1] = __builtin_amdgcn_mfma_f32_32x32x16_bf16(ah0, BS[1], acc[0][1], 0, 0, 0); \
    acc[1][0] = __builtin_amdgcn_mfma_f32_32x32x16_bf16(ah1, BS[0], acc[1][0], 0, 0, 0); \
    acc[1][1] = __builtin_amdgcn_mfma_f32_32x32x16_bf16(ah1, BS[1], acc[1][1], 0, 0, 0); \
    acc[0][0] = __builtin_amdgcn_mfma_f32_32x32x16_bf16(ah0, BS[2], acc[0][0], 0, 0, 0); \
    acc[0][1] = __builtin_amdgcn_mfma_f32_32x32x16_bf16(ah0, BS[3], acc[0][1], 0, 0, 0); \
    acc[1][0] = __builtin_amdgcn_mfma_f32_32x32x16_bf16(ah1, BS[2], acc[1][0], 0, 0, 0); \
    acc[1][1] = __builtin_amdgcn_mfma_f32_32x32x16_bf16(ah1, BS[3], acc[1][1], 0, 0, 0); \
    acc[0][0] = __builtin_amdgcn_mfma_f32_32x32x16_bf16(al0, BS[0], acc[0][0], 0, 0, 0); \
    acc[0][1] = __builtin_amdgcn_mfma_f32_32x32x16_bf16(al0, BS[1], acc[0][1], 0, 0, 0); \
    acc[1][0] = __builtin_amdgcn_mfma_f32_32x32x16_bf16(al1, BS[0], acc[1][0], 0, 0, 0); \
    acc[1][1] = __builtin_amdgcn_mfma_f32_32x32x16_bf16(al1, BS[1], acc[1][1], 0, 0, 0); }

    const int NT = K >> 5;
    loadA(0);
    LOADB(b0, 0);
    LOADB(b1, 1);
    stageA(0);
    __syncthreads();
    loadA(32);

    for (int t = 0; t < NT; ++t) {
        const int bufc = t & 1;
        const int k4a = (2 * t + 2 < KD16) ? 2 * t + 2 : KD16 - 1;
        const int k4b = (2 * t + 3 < KD16) ? 2 * t + 3 : KD16 - 1;
        __builtin_amdgcn_s_setprio(1);
        COMPUTE_KS(0, b0);
        LOADB(b0, k4a);
        COMPUTE_KS(1, b1);
        LOADB(b1, k4b);
        __builtin_amdgcn_s_setprio(0);
        if (t + 1 < NT) {
            stageA((t + 1) & 1);
            __syncthreads();
            if (t + 2 < NT) loadA((t + 2) << 5);
        }
    }

#undef LOADB
#undef AFRAG
#undef COMPUTE_KS

    // epilogue: C/D 32x32 layout: col = lane&31, row = (e&3)+8*(e>>2)+4*(lane>>5)
#pragma unroll
    for (int mi = 0; mi < 2; ++mi) {
        const int rbase = brow + wr * 64 + mi * 32 + 4 * lhi;
#pragma unroll
        for (int ni = 0; ni < 2; ++ni) {
            const int c = bcol + wc * 64 + ni * 32 + l31;
            float bv = 0.f;
            if (BIAS) {
                const long long bo = biasBase + c;
                bv = bfBias ? bf2f(((const unsigned short*)biasv)[bo])
                            : ((const float*)biasv)[bo];
            }
#pragma unroll
            for (int e = 0; e < 16; ++e) {
                const int r = rbase + (e & 3) + 8 * (e >> 2);
                float v = acc[mi][ni][e];
                if (BIAS) v += bv;
                if (MASK) v = (c >= r) ? v * scale : -1e30f;
                if (RELU) v = fmaxf(v, 0.f);
                const long long off = zC + (long long)r * N + c;
                if (bfC) ((__hip_bfloat16*)Cv)[off] = __float2bfloat16(v);
                else     ((float*)Cv)[off] = v;
            }
        }
    }
}

__global__ __launch_bounds__(256)
void softmax_k(float* __restrict__ Sc) {
    float* row = Sc + (long long)blockIdx.y * SEQ * SEQ + (long long)blockIdx.x * SEQ;
    const int tid = threadIdx.x;

    float v[8];
    float m = -1e30f;
#pragma unroll
    for (int i = 0; i < 8; ++i) { v[i] = row[tid + i * 256]; m = fmaxf(m, v[i]); }
#pragma unroll
    for (int off = 32; off > 0; off >>= 1) m = fmaxf(m, __shfl_down(m, off));

    __shared__ float sm[4];
    __shared__ float ss[4];
    const int wid = tid >> 6, lane = tid & 63;
    if (lane == 0) sm[wid] = m;
    __syncthreads();
    const float mAll = fmaxf(fmaxf(sm[0], sm[1]), fmaxf(sm[2], sm[3]));

    float s = 0.f;
#pragma unroll
    for (int i = 0; i < 8; ++i) { v[i] = __expf(v[i] - mAll); s += v[i]; }
#pragma unroll
    for (int off = 32; off > 0; off >>= 1) s += __shfl_down(s, off);
    if (lane == 0) ss[wid] = s;
    __syncthreads();
    const float inv = 1.f / (ss[0] + ss[1] + ss[2] + ss[3]);
#pragma unroll
    for (int i = 0; i < 8; ++i) row[tid + i * 256] = v[i] * inv;
}

extern "C" void kernel_launch(void* const* d_in, const int* in_sizes, int n_in,
                              void* d_out, int out_size, void* d_ws, size_t ws_size,
                              hipStream_t stream) {
    const int*  x   = (const int*)d_in[0];
    const void* emb = d_in[1];
    const void* Wq  = d_in[2];
    const void* bq  = d_in[3];
    const void* Wk  = d_in[4];
    const void* bk  = d_in[5];
    const void* Wv  = d_in[6];
    const void* bv  = d_in[7];
    const void* W1  = d_in[8];
    const void* b1  = d_in[9];
    const void* W2  = d_in[10];
    const void* b2  = d_in[11];

    char* ws = (char*)d_ws;
    const long long SZ = 33554432LL;  // 32 MB slots
    // Slot plan (7*SZ + 4 total):
    //  0: h           -> mid[0]        4: wslq (QKV wts) -> sc hi / pong
    //  1: q           -> mid[1]        5: kxs            -> wsl (MLP wts)
    //  2: kx f32 -> vxs -> mid[2]      6: att (cur/flip)
    //  3: vx f32 -> sc lo -> mid[3]    7*SZ: flag
    float* h    = (float*)(ws);
    float* q    = (float*)(ws + SZ);
    float* kx   = (float*)(ws + 2 * SZ);
    float* vx   = (float*)(ws + 3 * SZ);
    float* sc   = (float*)(ws + 3 * SZ);                    // [3SZ,5SZ) after vx dead
    float* mid  = h;                                        // slots 0-3 in MLP
    float* pong = (float*)(ws + 4 * SZ);
    float* att  = (float*)(ws + 6 * SZ);
    unsigned short* vxs_h = (unsigned short*)(ws + 2 * SZ); // slot 2 (kx dead)
    unsigned short* vxs_l = vxs_h + 8388608;
    unsigned short* kxs_h = (unsigned short*)(ws + 5 * SZ); // slot 5
    unsigned short* kxs_l = kxs_h + 8388608;
    unsigned short* wslq_h = (unsigned short*)(ws + 4 * SZ); // QKV weights (4MB)
    unsigned short* wslq_l = wslq_h + 1048576;
    unsigned short* wsl_h = (unsigned short*)(ws + 5 * SZ);  // MLP weights (kxs dead)
    unsigned short* wsl_l = wsl_h + 4194304;
    int* flag = (int*)(ws + 7 * SZ);

    const dim3 b256(256);
    const long long SE = (long long)SEQ * EDIM;
    const long long SS = (long long)SEQ * SEQ;
    const long long TSE = 2097152LL;   // tiled per-batch elems (2048*1024)

    sniff_k<<<1, 64, 0, stream>>>((const unsigned int*)emb, flag);
    gather_k<<<ROWS, b256, 0, stream>>>(x, emb, h, flag);

    // QKV: weight -> split^T tiled (slot 4), then MFMA GEMM
    splitT_tiled_k<<<dim3(32, 32, 1), b256, 0, stream>>>(
        Wq, wslq_h, wslq_l, EDIM, EDIM, 0, 0, 0, flag, 1);
    mgemm_k<true, false, false><<<dim3(EDIM / BN, ROWS / BM, 1), b256, 0, stream>>>(
        h, wslq_h, wslq_l, bq, q, ROWS, EDIM, EDIM, 0, 0, 0, 0, 1.f, flag, 1, 0);
    splitT_tiled_k<<<dim3(32, 32, 1), b256, 0, stream>>>(
        Wk, wslq_h, wslq_l, EDIM, EDIM, 0, 0, 0, flag, 1);
    mgemm_k<true, false, false><<<dim3(EDIM / BN, ROWS / BM, 1), b256, 0, stream>>>(
        h, wslq_h, wslq_l, bk, kx, ROWS, EDIM, EDIM, 0, 0, 0, 0, 1.f, flag, 1, 0);
    splitT_tiled_k<<<dim3(32, 32, 1), b256, 0, stream>>>(
        Wv, wslq_h, wslq_l, EDIM, EDIM, 0, 0, 0, flag, 1);
    mgemm_k<true, false, false><<<dim3(EDIM / BN, ROWS / BM, 1), b256, 0, stream>>>(
        h, wslq_h, wslq_l, bv, vx, ROWS, EDIM, EDIM, 0, 0, 0, 0, 1.f, flag, 1, 0);

    // K rows -> tiled split (slot 5); V -> transpose+tiled split (slot 2)
    splitrows_tiled_k<<<ROWS / 2, b256, 0, stream>>>(kx, kxs_h, kxs_l);
    splitT_tiled_k<<<dim3(32, 64, NB), b256, 0, stream>>>(
        vx, vxs_h, vxs_l, SEQ, EDIM, 0, SE, TSE, flag, 0);

    // scores = (q @ k^T) * scale, suffix mask
    mgemm_k<false, false, true><<<dim3(SEQ / BN, SEQ / BM, NB), b256, 0, stream>>>(
        q, kxs_h, kxs_l, nullptr, sc, SEQ, SEQ, EDIM, SE, TSE, SS, 0, 0.03125f, flag, 0, 0);

    softmax_k<<<dim3(SEQ, NB), b256, 0, stream>>>(sc);

    // att = relu(w @ v)
    mgemm_k<false, true, false><<<dim3(EDIM / BN, SEQ / BM, NB), b256, 0, stream>>>(
        sc, vxs_h, vxs_l, nullptr, att, SEQ, EDIM, SEQ, SS, TSE, SE, 0, 1.f, flag, 0, 0);

    // MLP
    const float* cur = att;
    for (int i = 0; i < 4; ++i) {
        splitT_tiled_k<<<dim3(128, 32, 1), b256, 0, stream>>>(
            W1, wsl_h, wsl_l, EDIM, MDIM, (long long)i * EDIM * MDIM, 0, 0, flag, 1);
        mgemm_k<true, true, false><<<dim3(MDIM / BN, ROWS / BM, 1), b256, 0, stream>>>(
            cur, wsl_h, wsl_l, b1, mid, ROWS, MDIM, EDIM, 0, 0, 0,
            (long long)i * MDIM, 1.f, flag, 1, 0);

        splitT_tiled_k<<<dim3(32, 128, 1), b256, 0, stream>>>(
            W2, wsl_h, wsl_l, MDIM, EDIM, (long long)i * MDIM * EDIM, 0, 0, flag, 1);
        if (i < 3) {
            float* out = (cur == att) ? pong : att;
            mgemm_k<true, true, false><<<dim3(EDIM / BN, ROWS / BM, 1), b256, 0, stream>>>(
                mid, wsl_h, wsl_l, b2, out, ROWS, EDIM, MDIM, 0, 0, 0,
                (long long)i * EDIM, 1.f, flag, 1, 0);
            cur = out;
        } else {
            mgemm_k<true, true, false><<<dim3(EDIM / BN, ROWS / BM, 1), b256, 0, stream>>>(
                mid, wsl_h, wsl_l, b2, d_out, ROWS, EDIM, MDIM, 0, 0, 0,
                (long long)i * EDIM, 1.f, flag, 1, 1);
        }
    }
}

// Round 3
// 2313.880 us; speedup vs baseline: 3.5777x; 1.0743x over previous
//
#include <hip/hip_runtime.h>
#include <hip/hip_bf16.h>

#define EDIM 1024
#define MDIM 4096
#define SEQ  2048
#define NB   4
#define ROWS 8192

#define BM 128
#define BN 128

typedef short bh8 __attribute__((ext_vector_type(8)));
typedef float f32x16 __attribute__((ext_vector_type(16)));

__device__ __forceinline__ float bf2f(unsigned short u) {
    return __uint_as_float(((unsigned int)u) << 16);
}
__device__ __forceinline__ unsigned short f2bf(float f) {
    unsigned int u = __float_as_uint(f);
    u += 0x7FFFu + ((u >> 16) & 1u);
    return (unsigned short)(u >> 16);
}
__device__ __forceinline__ void splitf(float v, unsigned short& h, unsigned short& l) {
    h = f2bf(v);
    l = f2bf(v - __uint_as_float(((unsigned int)h) << 16));
}
__device__ __forceinline__ void ld4f(const float* __restrict__ p, float* d) {
    const float4 v = *reinterpret_cast<const float4*>(p);
    d[0] = v.x; d[1] = v.y; d[2] = v.z; d[3] = v.w;
}
__device__ __forceinline__ void ld4h(const unsigned short* __restrict__ p, float* d) {
    const ushort4 v = *reinterpret_cast<const ushort4*>(p);
    d[0] = bf2f(v.x); d[1] = bf2f(v.y); d[2] = bf2f(v.z); d[3] = bf2f(v.w);
}

// async global->LDS, 16B per lane
__device__ __forceinline__ void async_copy16(void* lds, const void* g) {
    __builtin_amdgcn_global_load_lds(
        (const __attribute__((address_space(1))) unsigned int*)g,
        (__attribute__((address_space(3))) unsigned int*)lds, 16, 0, 0);
}

// B fragment-tiled index: element (n,k) of [N][K] lives at
// ((((n/32)*(K/16)+k/16)*2+(k/8)%2)*32 + n%32)*8 + k%8
__device__ __forceinline__ long long tidx8(int n, int k, int KD16) {
    return ((((long long)(n >> 5) * KD16 + (k >> 4)) * 2 + ((k >> 3) & 1)) * 32 + (n & 31)) * 8;
}

// A-layout: per (row r, 32-k chunk): 128B = 8x16B blocks (hi blocks 0-3, lo 4-7),
// stored at position blk ^ (r&7). Writer helper (element granularity).
__device__ __forceinline__ void awrite(unsigned short* __restrict__ A, long long rc,
                                       int r, int k, unsigned short h, unsigned short l) {
    const int sub = (k & 31) >> 3, kb = k & 7, rx = r & 7;
    A[rc + ((sub ^ rx) << 3) + kb] = h;
    A[rc + (((4 + sub) ^ rx) << 3) + kb] = l;
}

// dtype sniffer: flag=1 -> inputs are bf16, flag=0 -> f32
__global__ __launch_bounds__(64)
void sniff_k(const unsigned int* __restrict__ w, int* __restrict__ flag) {
    int ok = 0;
    const int base = threadIdx.x * 32;
#pragma unroll
    for (int i = 0; i < 32; ++i) {
        const unsigned int v = w[base + i];
        const unsigned int lo = v & 0xFFFFu, hi = v >> 16;
        const unsigned int el = (lo >> 7) & 0xFF, eh = (hi >> 7) & 0xFF;
        const bool okl = (lo == 0u) || (el >= 0x30u && el <= 0x7Eu);
        const bool okh = (hi == 0u) || (eh >= 0x30u && eh <= 0x7Eu);
        ok += (okl && okh) ? 1 : 0;
    }
#pragma unroll
    for (int off = 32; off > 0; off >>= 1) ok += __shfl_down(ok, off);
    if (threadIdx.x == 0) *flag = (ok > 1400) ? 1 : 0;
}

// embedding gather -> h in A-layout (split)
__global__ __launch_bounds__(256)
void gather_k(const int* __restrict__ x, const void* __restrict__ emb,
              unsigned short* __restrict__ hA, const int* __restrict__ flagp) {
    const int bf = *flagp;
    const int row = blockIdx.x;
    const int idx = x[row];
    const int k = threadIdx.x * 4;
    const long long off = (long long)idx * EDIM + k;
    float d[4];
    if (bf) ld4h((const unsigned short*)emb + off, d);
    else    ld4f((const float*)emb + off, d);
    unsigned short h0, l0, h1, l1, h2, l2, h3, l3;
    splitf(d[0], h0, l0); splitf(d[1], h1, l1);
    splitf(d[2], h2, l2); splitf(d[3], h3, l3);
    const int rx = row & 7, sub = (k & 31) >> 3, kb = k & 7;
    const long long rc = ((long long)row * 32 + (k >> 5)) * 64;
    *reinterpret_cast<ushort4*>(hA + rc + ((sub ^ rx) << 3) + kb) = make_ushort4(h0, h1, h2, h3);
    *reinterpret_cast<ushort4*>(hA + rc + (((4 + sub) ^ rx) << 3) + kb) = make_ushort4(l0, l1, l2, l3);
}

// Weights: transpose + split + fragment-tile: in [Kd,Nd] -> hi/lo tiled [Nd,Kd]
__global__ __launch_bounds__(256)
void splitT_tiled_k(const void* __restrict__ in, unsigned short* __restrict__ oh,
                    unsigned short* __restrict__ ol, int Kd, int Nd,
                    long long inOff, const int* __restrict__ flagp, int bF) {
    const int bf = bF ? *flagp : 0;
    const int k0 = blockIdx.y * 32, n0 = blockIdx.x * 32;
    const int KD16 = Kd >> 4;
    __shared__ float t[32][33];
    const int c = threadIdx.x & 31, r0 = threadIdx.x >> 5;
#pragma unroll
    for (int i = 0; i < 4; ++i) {
        const int r = r0 + i * 8;
        const long long off = inOff + (long long)(k0 + r) * Nd + n0 + c;
        t[r][c] = bf ? bf2f(((const unsigned short*)in)[off]) : ((const float*)in)[off];
    }
    __syncthreads();
#pragma unroll
    for (int i = 0; i < 4; ++i) {
        const int r = r0 + i * 8;
        const float v = t[c][r];
        unsigned short hh, ll;
        splitf(v, hh, ll);
        const int n = n0 + r, k = k0 + c;
        const long long oo = tidx8(n, k, KD16) + (k & 7);
        oh[oo] = hh; ol[oo] = ll;
    }
}

// Split-bf16 MFMA GEMM. A pre-split A-layout (global pre-swizzled, staged to LDS
// via global_load_lds). B pre-split fragment-tiled, direct global->reg.
// OM: 0 = f32/bf16 C, 1 = A-layout out, 2 = B-layout out, 3 = B^T-layout out.
template<int OM, bool BIAS, bool RELU, bool MASK>
__global__ __launch_bounds__(256, 3)
void mgemm_k(const unsigned short* __restrict__ A,
             const unsigned short* __restrict__ Bh,
             const unsigned short* __restrict__ Bl,
             const void* __restrict__ biasv,
             void* __restrict__ Cv, void* __restrict__ Cv2,
             int M, int N, int K,
             long long sA, long long sB, long long sC,
             long long biasBase, float scale, int oKD16, long long zOut,
             const int* __restrict__ flagp, int bF, int cF) {
    const int flag = *flagp;
    const int bfBias = bF ? flag : 0;
    const int bfC = cF ? flag : 0;

    A  += (long long)blockIdx.z * sA;
    Bh += (long long)blockIdx.z * sB;
    Bl += (long long)blockIdx.z * sB;
    const long long zC = (long long)blockIdx.z * sC;

    // XCD remap
    const int GX = gridDim.x;
    const int f = blockIdx.y * GX + blockIdx.x;
    const int gxpc = GX >> 3;
    const int xcd = f & 7, p = f >> 3;
    const int bx = xcd * gxpc + (p % gxpc);
    const int by = p / gxpc;
    const int brow = by * BM, bcol = bx * BN;

    const int tid = threadIdx.x;
    const int lane = tid & 63, wave = tid >> 6;
    const int wr = wave >> 1, wc = wave & 1;
    const int l31 = lane & 31, lhi = lane >> 5;

    if (MASK && (bcol + BN - 1 < brow)) {
#pragma unroll
        for (int mi = 0; mi < 2; ++mi) {
            const int rbase = brow + wr * 64 + mi * 32 + 4 * lhi;
#pragma unroll
            for (int ni = 0; ni < 2; ++ni) {
                const int c = bcol + wc * 64 + ni * 32 + l31;
#pragma unroll
                for (int e = 0; e < 16; ++e) {
                    const int r = rbase + (e & 3) + 8 * (e >> 2);
                    ((float*)Cv)[zC + (long long)r * N + c] = -1e30f;
                }
            }
        }
        return;
    }

    __shared__ __align__(16) char Ash[2][BM * 128];   // 2 x 16KB

    f32x16 acc[2][2];
#pragma unroll
    for (int a = 0; a < 2; ++a)
#pragma unroll
        for (int b = 0; b < 2; ++b)
#pragma unroll
            for (int e = 0; e < 16; ++e) acc[a][b][e] = 0.f;

    const int CH = K >> 5;        // 32-k chunks per row (= number of K tiles)
    const int KD16 = K >> 4;

    const long long bbase0 = ((long long)((bcol >> 5) + wc * 2 + 0) * KD16) * 512 + lane * 8;
    const long long bbase1 = ((long long)((bcol >> 5) + wc * 2 + 1) * KD16) * 512 + lane * 8;

    bh8 b0[4], b1[4];   // [h(ni0), h(ni1), l(ni0), l(ni1)]

    auto stageA = [&](int buf, int chunk) {
        char* lb = &Ash[buf][0] + tid * 16;
        const char* gb = (const char*)A;
#pragma unroll
        for (int i = 0; i < 4; ++i) {
            const int m = (tid >> 3) + i * 32;
            const long long src = (((long long)(brow + m) * CH + chunk) << 7) + ((tid & 7) << 4);
            async_copy16(lb + i * 4096, gb + src);
        }
    };

#define LOADB(dst, k4v) { \
    const long long kk_ = (long long)(k4v) * 512; \
    dst[0] = *reinterpret_cast<const bh8*>(Bh + bbase0 + kk_); \
    dst[1] = *reinterpret_cast<const bh8*>(Bh + bbase1 + kk_); \
    dst[2] = *reinterpret_cast<const bh8*>(Bl + bbase0 + kk_); \
    dst[3] = *reinterpret_cast<const bh8*>(Bl + bbase1 + kk_); }

#define AFRAG(dsth, dstl, MI) { \
    const int r_ = wr * 64 + (MI) * 32 + l31; \
    const char* base_ = &Ash[bufc][0] + r_ * 128; \
    dsth = *reinterpret_cast<const bh8*>(base_ + (((kb) ^ (r_ & 7)) << 4)); \
    dstl = *reinterpret_cast<const bh8*>(base_ + (((4 + kb) ^ (r_ & 7)) << 4)); }

#define COMPUTE_KS(KS, BS) { \
    const int kb = (KS) * 2 + lhi; \
    bh8 ah0, al0, ah1, al1; \
    AFRAG(ah0, al0, 0); AFRAG(ah1, al1, 1); \
    acc[0][0] = __builtin_amdgcn_mfma_f32_32x32x16_bf16(ah0, BS[0], acc[0][0], 0, 0, 0); \
    acc[0][1] = __builtin_amdgcn_mfma_f32_32x32x16_bf16(ah0, BS[1], acc[0][1], 0, 0, 0); \
    acc[1][0] = __builtin_amdgcn_mfma_f32_32x32x16_bf16(ah1, BS[0], acc[1][0], 0, 0, 0); \
    acc[1][1] = __builtin_amdgcn_mfma_f32_32x32x16_bf16(ah1, BS[1], acc[1][1], 0, 0, 0); \
    acc[0][0] = __builtin_amdgcn_mfma_f32_32x32x16_bf16(ah0, BS[2], acc[0][0], 0, 0, 0); \
    acc[0][1] = __builtin_amdgcn_mfma_f32_32x32x16_bf16(ah0, BS[3], acc[0][1], 0, 0, 0); \
    acc[1][0] = __builtin_amdgcn_mfma_f32_32x32x16_bf16(ah1, BS[2], acc[1][0], 0, 0, 0); \
    acc[1][1] = __builtin_amdgcn_mfma_f32_32x32x16_bf16(ah1, BS[3], acc[1][1], 0, 0, 0); \
    acc[0][0] = __builtin_amdgcn_mfma_f32_32x32x16_bf16(al0, BS[0], acc[0][0], 0, 0, 0); \
    acc[0][1] = __builtin_amdgcn_mfma_f32_32x32x16_bf16(al0, BS[1], acc[0][1], 0, 0, 0); \
    acc[1][0] = __builtin_amdgcn_mfma_f32_32x32x16_bf16(al1, BS[0], acc[1][0], 0, 0, 0); \
    acc[1][1] = __builtin_amdgcn_mfma_f32_32x32x16_bf16(al1, BS[1], acc[1][1], 0, 0, 0); }

    const int NT = CH;
    LOADB(b0, 0);
    LOADB(b1, 1);
    stageA(0, 0);
    __syncthreads();

    for (int t = 0; t < NT; ++t) {
        const int bufc = t & 1;
        if (t + 1 < NT) stageA((t + 1) & 1, t + 1);
        const int k4a = (2 * t + 2 < KD16) ? 2 * t + 2 : KD16 - 1;
        const int k4b = (2 * t + 3 < KD16) ? 2 * t + 3 : KD16 - 1;
        __builtin_amdgcn_s_setprio(1);
        COMPUTE_KS(0, b0);
        LOADB(b0, k4a);
        COMPUTE_KS(1, b1);
        LOADB(b1, k4b);
        __builtin_amdgcn_s_setprio(0);
        __syncthreads();
    }

#undef LOADB
#undef AFRAG
#undef COMPUTE_KS

    // epilogue: C/D 32x32: col = lane&31, row = (e&3)+8*(e>>2)+4*(lane>>5)
#pragma unroll
    for (int mi = 0; mi < 2; ++mi) {
        const int rbase = brow + wr * 64 + mi * 32 + 4 * lhi;
#pragma unroll
        for (int ni = 0; ni < 2; ++ni) {
            const int c = bcol + wc * 64 + ni * 32 + l31;
            float bv = 0.f;
            if (BIAS) {
                const long long bo = biasBase + c;
                bv = bfBias ? bf2f(((const unsigned short*)biasv)[bo])
                            : ((const float*)biasv)[bo];
            }
            if constexpr (OM == 3) {
#pragma unroll
                for (int g = 0; g < 4; ++g) {
                    const int t0 = rbase + 8 * g;
                    const int z = t0 >> 11, tt = t0 & 2047;
                    float vv[4];
#pragma unroll
                    for (int d = 0; d < 4; ++d) {
                        float v = acc[mi][ni][g * 4 + d];
                        if (BIAS) v += bv;
                        if (RELU) v = fmaxf(v, 0.f);
                        vv[d] = v;
                    }
                    unsigned short h0, l0, h1, l1, h2, l2, h3, l3;
                    splitf(vv[0], h0, l0); splitf(vv[1], h1, l1);
                    splitf(vv[2], h2, l2); splitf(vv[3], h3, l3);
                    const long long o = (long long)z * zOut +
                        (((long long)(c >> 5) * oKD16 + (tt >> 4)) * 2 + ((tt >> 3) & 1)) * 256 +
                        (c & 31) * 8 + (tt & 7);
                    *reinterpret_cast<ushort4*>((unsigned short*)Cv + o) = make_ushort4(h0, h1, h2, h3);
                    *reinterpret_cast<ushort4*>((unsigned short*)Cv2 + o) = make_ushort4(l0, l1, l2, l3);
                }
            } else {
#pragma unroll
                for (int e = 0; e < 16; ++e) {
                    const int r = rbase + (e & 3) + 8 * (e >> 2);
                    float v = acc[mi][ni][e];
                    if (BIAS) v += bv;
                    if (MASK) v = (c >= r) ? v * scale : -1e30f;
                    if (RELU) v = fmaxf(v, 0.f);
                    if constexpr (OM == 0) {
                        const long long off = zC + (long long)r * N + c;
                        if (bfC) ((__hip_bfloat16*)Cv)[off] = __float2bfloat16(v);
                        else     ((float*)Cv)[off] = v;
                    } else if constexpr (OM == 1) {
                        unsigned short hh, ll;
                        splitf(v, hh, ll);
                        const long long rc = zC + ((long long)r * (N >> 5) + (c >> 5)) * 64;
                        awrite((unsigned short*)Cv, rc, r, c, hh, ll);
                    } else {  // OM == 2
                        unsigned short hh, ll;
                        splitf(v, hh, ll);
                        const int z = r >> 11, n = r & 2047;
                        const long long o = (long long)z * zOut +
                            (((long long)(n >> 5) * oKD16 + (c >> 4)) * 2 + ((c >> 3) & 1)) * 256 +
                            (n & 31) * 8 + (c & 7);
                        ((unsigned short*)Cv)[o] = hh;
                        ((unsigned short*)Cv2)[o] = ll;
                    }
                }
            }
        }
    }
}

// softmax over f32 scores row -> split A-layout (K=2048) output
__global__ __launch_bounds__(256)
void softmax_k(const float* __restrict__ Sc, unsigned short* __restrict__ W) {
    const int m = blockIdx.x, z = blockIdx.y;
    const float* row = Sc + ((long long)z * SEQ + m) * SEQ;
    const int tid = threadIdx.x;

    float v[8];
    float mx = -1e30f;
#pragma unroll
    for (int i = 0; i < 8; ++i) { v[i] = row[tid + i * 256]; mx = fmaxf(mx, v[i]); }
#pragma unroll
    for (int off = 32; off > 0; off >>= 1) mx = fmaxf(mx, __shfl_down(mx, off));

    __shared__ float sm[4];
    __shared__ float ss[4];
    const int wid = tid >> 6, lane = tid & 63;
    if (lane == 0) sm[wid] = mx;
    __syncthreads();
    const float mAll = fmaxf(fmaxf(sm[0], sm[1]), fmaxf(sm[2], sm[3]));

    float s = 0.f;
#pragma unroll
    for (int i = 0; i < 8; ++i) { v[i] = __expf(v[i] - mAll); s += v[i]; }
#pragma unroll
    for (int off = 32; off > 0; off >>= 1) s += __shfl_down(s, off);
    if (lane == 0) ss[wid] = s;
    __syncthreads();
    const float inv = 1.f / (ss[0] + ss[1] + ss[2] + ss[3]);

    unsigned short* Wb = W + (long long)z * (SEQ * 4096LL);
#pragma unroll
    for (int i = 0; i < 8; ++i) {
        const int k = tid + i * 256;
        unsigned short hh, ll;
        splitf(v[i] * inv, hh, ll);
        const long long rc = ((long long)m * 64 + (k >> 5)) * 64;
        awrite(Wb, rc, m, k, hh, ll);
    }
}

extern "C" void kernel_launch(void* const* d_in, const int* in_sizes, int n_in,
                              void* d_out, int out_size, void* d_ws, size_t ws_size,
                              hipStream_t stream) {
    const int*  x   = (const int*)d_in[0];
    const void* emb = d_in[1];
    const void* Wq  = d_in[2];
    const void* bq  = d_in[3];
    const void* Wk  = d_in[4];
    const void* bk  = d_in[5];
    const void* Wv  = d_in[6];
    const void* bv  = d_in[7];
    const void* W1  = d_in[8];
    const void* b1  = d_in[9];
    const void* W2  = d_in[10];
    const void* b2  = d_in[11];

    char* ws = (char*)d_ws;
    const long long SZ = 33554432LL;
    // Slots:  0: hA -> watt(0-1) -> mid(0-3)     4: sc(4-5) -> att -> W2out ping
    //         1: qA -> watt                      5: sc -> W1/W2 weights
    //         2: kxs                             6: Wqkv -> W2out pong
    //         3: vxs                             7*SZ: flag
    unsigned short* hA    = (unsigned short*)(ws);
    unsigned short* qA    = (unsigned short*)(ws + SZ);
    unsigned short* kxs_h = (unsigned short*)(ws + 2 * SZ);
    unsigned short* kxs_l = kxs_h + 8388608;
    unsigned short* vxs_h = (unsigned short*)(ws + 3 * SZ);
    unsigned short* vxs_l = vxs_h + 8388608;
    float*          sc    = (float*)(ws + 4 * SZ);
    unsigned short* watt  = (unsigned short*)(ws);
    unsigned short* att   = (unsigned short*)(ws + 4 * SZ);
    unsigned short* wmlp  = (unsigned short*)(ws + 5 * SZ);
    unsigned short* w1_h  = wmlp,              * w1_l = wmlp + 4194304;
    unsigned short* w2_h  = wmlp + 8388608,    * w2_l = wmlp + 12582912;
    unsigned short* mid   = (unsigned short*)(ws);
    unsigned short* wqkv  = (unsigned short*)(ws + 6 * SZ);
    unsigned short* wq_h = wqkv,           * wq_l = wqkv + 1048576;
    unsigned short* wk_h = wqkv + 2097152, * wk_l = wqkv + 3145728;
    unsigned short* wv_h = wqkv + 4194304, * wv_l = wqkv + 5242880;
    unsigned short* out6  = (unsigned short*)(ws + 6 * SZ);
    int* flag = (int*)(ws + 7 * SZ);

    const dim3 b256(256);
    const long long SS = (long long)SEQ * SEQ;
    const long long TSE = 2097152LL;   // B-layout per-batch elems (2048*1024)

    sniff_k<<<1, 64, 0, stream>>>((const unsigned int*)emb, flag);
    gather_k<<<ROWS, b256, 0, stream>>>(x, emb, hA, flag);

    splitT_tiled_k<<<dim3(32, 32, 1), b256, 0, stream>>>(Wq, wq_h, wq_l, EDIM, EDIM, 0, flag, 1);
    splitT_tiled_k<<<dim3(32, 32, 1), b256, 0, stream>>>(Wk, wk_h, wk_l, EDIM, EDIM, 0, flag, 1);
    splitT_tiled_k<<<dim3(32, 32, 1), b256, 0, stream>>>(Wv, wv_h, wv_l, EDIM, EDIM, 0, flag, 1);

    // q -> A-layout
    mgemm_k<1, true, false, false><<<dim3(8, 64, 1), b256, 0, stream>>>(
        hA, wq_h, wq_l, bq, qA, nullptr, ROWS, EDIM, EDIM,
        0, 0, 0, 0, 1.f, 0, 0, flag, 1, 0);
    // k -> B-layout (scores consumer: K=1024, KD16=64)
    mgemm_k<2, true, false, false><<<dim3(8, 64, 1), b256, 0, stream>>>(
        hA, wk_h, wk_l, bk, kxs_h, kxs_l, ROWS, EDIM, EDIM,
        0, 0, 0, 0, 1.f, 64, TSE, flag, 1, 0);
    // v -> B^T layout (PV consumer: K=2048, KD16=128)
    mgemm_k<3, true, false, false><<<dim3(8, 64, 1), b256, 0, stream>>>(
        hA, wv_h, wv_l, bv, vxs_h, vxs_l, ROWS, EDIM, EDIM,
        0, 0, 0, 0, 1.f, 128, TSE, flag, 1, 0);

    // scores = (q @ k^T) * scale, suffix mask -> f32
    mgemm_k<0, false, false, true><<<dim3(16, 16, NB), b256, 0, stream>>>(
        qA, kxs_h, kxs_l, nullptr, sc, nullptr, SEQ, SEQ, EDIM,
        4194304LL, TSE, SS, 0, 0.03125f, 0, 0, flag, 0, 0);

    softmax_k<<<dim3(SEQ, NB), b256, 0, stream>>>(sc, watt);

    // att = relu(w @ v) -> A-layout
    mgemm_k<1, false, true, false><<<dim3(8, 16, NB), b256, 0, stream>>>(
        watt, vxs_h, vxs_l, nullptr, att, nullptr, SEQ, EDIM, SEQ,
        8388608LL, TSE, 4194304LL, 0, 1.f, 0, 0, flag, 0, 0);

    // MLP
    const unsigned short* cur = att;
    for (int i = 0; i < 4; ++i) {
        splitT_tiled_k<<<dim3(128, 32, 1), b256, 0, stream>>>(
            W1, w1_h, w1_l, EDIM, MDIM, (long long)i * EDIM * MDIM, flag, 1);
        mgemm_k<1, true, true, false><<<dim3(32, 64, 1), b256, 0, stream>>>(
            cur, w1_h, w1_l, b1, mid, nullptr, ROWS, MDIM, EDIM,
            0, 0, 0, (long long)i * MDIM, 1.f, 0, 0, flag, 1, 0);

        splitT_tiled_k<<<dim3(32, 128, 1), b256, 0, stream>>>(
            W2, w2_h, w2_l, MDIM, EDIM, (long long)i * MDIM * EDIM, flag, 1);
        if (i < 3) {
            unsigned short* out = (cur == att) ? out6 : att;
            mgemm_k<1, true, true, false><<<dim3(8, 64, 1), b256, 0, stream>>>(
                mid, w2_h, w2_l, b2, out, nullptr, ROWS, EDIM, MDIM,
                0, 0, 0, (long long)i * EDIM, 1.f, 0, 0, flag, 1, 0);
            cur = out;
        } else {
            mgemm_k<0, true, true, false><<<dim3(8, 64, 1), b256, 0, stream>>>(
                mid, w2_h, w2_l, b2, d_out, nullptr, ROWS, EDIM, MDIM,
                0, 0, 0, (long long)i * EDIM, 1.f, 0, 0, flag, 1, 1);
        }
    }
}